// Round 7
// baseline (375.029 us; speedup 1.0000x reference)
//
#include <hip/hip_runtime.h>
#include <math.h>

#define BB 32768
#define DD 512
#define CC 527
#define NTW 17     // tiles per wave (one col-half)
#define NCOL 544   // 34 tiles of 16
#define BM 32      // rows per block (2 row-groups x 16)
#define BK 32      // k-tile
#define LDA 40     // LDS row stride in shorts (80B)

typedef __attribute__((ext_vector_type(8))) short bf16x8;
typedef __attribute__((ext_vector_type(4))) short bf16x4;
typedef __attribute__((ext_vector_type(4))) float f32x4;

// Named-SSA accumulators (R6 lesson: f32x4 arrays never SROA-promote -> scratch)
#define FOREACH_T(OP) OP(0) OP(1) OP(2) OP(3) OP(4) OP(5) OP(6) OP(7) OP(8) \
  OP(9) OP(10) OP(11) OP(12) OP(13) OP(14) OP(15) OP(16)

#if __has_builtin(__builtin_amdgcn_exp2f)
#define EXP2F(v) __builtin_amdgcn_exp2f(v)
#else
#define EXP2F(v) exp2f(v)
#endif
#if __has_builtin(__builtin_amdgcn_logf)
#define LOG2F(v) __builtin_amdgcn_logf(v)
#else
#define LOG2F(v) __log2f(v)
#endif

__device__ __forceinline__ short f2bf(float f) {  // fp32 -> bf16 RNE
  unsigned u = __float_as_uint(f);
  u += 0x7fffu + ((u >> 16) & 1u);
  return (short)(u >> 16);
}

template<bool PRE>
__global__ __launch_bounds__(256, 3)
void fused_mfma_bce_topk(const float* __restrict__ x, const float* __restrict__ y,
                         const float* __restrict__ W, const short* __restrict__ Wbf,
                         const float* __restrict__ bias, const float* __restrict__ pw,
                         float* __restrict__ accum) {
  __shared__ short As[BM * LDA];        // 2.5 KB
  __shared__ short Bs[NCOL * LDA];      // 42.5 KB
  __shared__ int   kcL[2][BM];
  __shared__ int   cntL[2][BM];
  __shared__ int   hitL[2][BM];
  __shared__ float redL[4], redS[4];

  const int tid  = threadIdx.x;
  const int wave = tid >> 6, lane = tid & 63;
  const int cl   = lane & 15, quad = lane >> 4;
  const int rg   = wave & 1;      // row-group (16 rows)
  const int chh  = wave >> 1;     // col-half (17 tiles)
  const int r0   = blockIdx.x * BM;
  const int rowbase = rg * 16 + quad * 4;   // local row of this quad's 4 rows

#define DECL(t) f32x4 A##t = (f32x4){0.f, 0.f, 0.f, 0.f};
  FOREACH_T(DECL)
#undef DECL

  const int arow = tid >> 3, aseg = tid & 7;

  // ---------------- MFMA GEMM over K = 512 ----------------
  for (int k0 = 0; k0 < DD; k0 += BK) {
    {  // A: 32 rows x 32 k, one f32x4 per thread
      const float* sA = x + (size_t)(r0 + arow) * DD + k0 + aseg * 4;
      f32x4 f = __builtin_nontemporal_load((const f32x4*)sA);
      bf16x4 v; v[0]=f2bf(f.x); v[1]=f2bf(f.y); v[2]=f2bf(f.z); v[3]=f2bf(f.w);
      *(bf16x4*)(&As[arow * LDA + aseg * 4]) = v;
    }
    if (PRE) {   // B: 544 x 32 from pre-converted bf16 W (rows>=527 are zero)
#pragma unroll
      for (int i = 0; i < 9; ++i) {
        int ch2 = tid + i * 256;
        if (ch2 < NCOL * 4) {
          int row = ch2 >> 2, sg = ch2 & 3;
          bf16x8 v = *(const bf16x8*)(Wbf + (size_t)row * DD + k0 + sg * 8);
          *(bf16x8*)(&Bs[row * LDA + sg * 8]) = v;
        }
      }
    } else {     // fallback: convert from f32 W in-kernel
#pragma unroll
      for (int i = 0; i < 17; ++i) {
        int ch2 = tid + i * 256;
        if (ch2 < NCOL * 8) {
          int row = ch2 >> 3, sg = ch2 & 7;
          bf16x4 v = {0, 0, 0, 0};
          if (row < CC) {
            f32x4 f = *(const f32x4*)(W + (size_t)row * DD + k0 + sg * 4);
            v[0]=f2bf(f.x); v[1]=f2bf(f.y); v[2]=f2bf(f.z); v[3]=f2bf(f.w);
          }
          *(bf16x4*)(&Bs[row * LDA + sg * 4]) = v;
        }
      }
    }
    __syncthreads();
    {
      bf16x8 af = *(const bf16x8*)(&As[(rg * 16 + cl) * LDA + quad * 8]);
#define MFSTEP(t) { \
      bf16x8 bfr = *(const bf16x8*)(&Bs[((chh * NTW + (t)) * 16 + cl) * LDA + quad * 8]); \
      A##t = __builtin_amdgcn_mfma_f32_16x16x32_bf16(af, bfr, A##t, 0, 0, 0); }
      FOREACH_T(MFSTEP)
#undef MFSTEP
    }
    __syncthreads();
  }

  // ---------------- Epilogue ----------------
  // C/D layout: col = (chh*17+t)*16 + cl ; local row = rg*16 + quad*4 + r
  const size_t growbase = (size_t)(r0 + rowbase);
  float lossloc = 0.f;
  unsigned ym[4] = {0u, 0u, 0u, 0u};

#define EPI(t) { \
    int col = (chh * NTW + (t)) * 16 + cl; \
    bool cv = (col < CC); \
    float bt = cv ? bias[col] : 0.f; \
    float pt = cv ? pw[col]   : 1.f; \
    _Pragma("unroll") \
    for (int r = 0; r < 4; ++r) { \
      float z = A##t[r] + bt; \
      if (cv) { \
        float yv = __builtin_nontemporal_load(&y[(growbase + r) * CC + col]); \
        float a  = fabsf(z); \
        float e  = EXP2F(a * -1.4426950408889634f); \
        float l1 = LOG2F(1.0f + e) * 0.6931471805599453f; \
        float sp_pos = fmaxf(z, 0.f) + l1; \
        float sp_neg = sp_pos - z; \
        lossloc += pt * yv * sp_neg + (1.f - yv) * sp_pos; \
        if (yv > 0.5f) ym[r] |= (1u << (t)); \
        A##t[r] = z; \
      } else { \
        A##t[r] = -1e30f; \
      } \
    } }
  FOREACH_T(EPI)
#undef EPI

  // per-row k: popcount over this col-half, cl-reduce, combine across halves
  unsigned pk01 = (unsigned)__popc(ym[0]) | ((unsigned)__popc(ym[1]) << 16);
  unsigned pk23 = (unsigned)__popc(ym[2]) | ((unsigned)__popc(ym[3]) << 16);
#pragma unroll
  for (int m = 1; m <= 8; m <<= 1) {
    pk01 += __shfl_xor(pk01, m, 64);
    pk23 += __shfl_xor(pk23, m, 64);
  }
  if (cl == 0) {
    kcL[chh][rowbase + 0] = (int)(pk01 & 0xffffu);
    kcL[chh][rowbase + 1] = (int)(pk01 >> 16);
    kcL[chh][rowbase + 2] = (int)(pk23 & 0xffffu);
    kcL[chh][rowbase + 3] = (int)(pk23 >> 16);
  }
  __syncthreads();
  int kr[4];
#pragma unroll
  for (int r = 0; r < 4; ++r) kr[r] = kcL[0][rowbase + r] + kcL[1][rowbase + r];

  // Bisection (27 fixed iters over [-32,32]; resolution 5e-7)
  float lo[4], hi[4], th[4];
  bool fnd[4];
#pragma unroll
  for (int r = 0; r < 4; ++r) { lo[r] = -32.f; hi[r] = 32.f; th[r] = 0.f; fnd[r] = false; }

  for (int it = 0; it < 27; ++it) {
    float tm[4];
#pragma unroll
    for (int r = 0; r < 4; ++r) tm[r] = 0.5f * (lo[r] + hi[r]);
    int c[4] = {0, 0, 0, 0};
#define CNT(t) { \
    _Pragma("unroll") \
    for (int r = 0; r < 4; ++r) c[r] += (A##t[r] > tm[r]) ? 1 : 0; }
    FOREACH_T(CNT)
#undef CNT
    unsigned p01 = (unsigned)c[0] | ((unsigned)c[1] << 16);
    unsigned p23 = (unsigned)c[2] | ((unsigned)c[3] << 16);
#pragma unroll
    for (int m = 1; m <= 8; m <<= 1) {
      p01 += __shfl_xor(p01, m, 64);
      p23 += __shfl_xor(p23, m, 64);
    }
    __syncthreads();   // prior iteration's cntL reads complete before overwrite
    if (cl == 0) {
      cntL[chh][rowbase + 0] = (int)(p01 & 0xffffu);
      cntL[chh][rowbase + 1] = (int)(p01 >> 16);
      cntL[chh][rowbase + 2] = (int)(p23 & 0xffffu);
      cntL[chh][rowbase + 3] = (int)(p23 >> 16);
    }
    __syncthreads();
#pragma unroll
    for (int r = 0; r < 4; ++r) {
      int tot = cntL[0][rowbase + r] + cntL[1][rowbase + r];
      if (!fnd[r]) {
        if (tot == kr[r])                          { th[r] = tm[r]; fnd[r] = true; }
        else if (tm[r] <= lo[r] || tm[r] >= hi[r]) { th[r] = lo[r]; fnd[r] = true; }
        else if (tot > kr[r])                      lo[r] = tm[r];
        else                                       hi[r] = tm[r];
      }
    }
  }
#pragma unroll
  for (int r = 0; r < 4; ++r) if (!fnd[r]) th[r] = lo[r];

  // hits among positives, combined across halves
  int h[4] = {0, 0, 0, 0};
#define HIT(t) { \
    _Pragma("unroll") \
    for (int r = 0; r < 4; ++r) \
      if (((ym[r] >> (t)) & 1u) && A##t[r] > th[r]) h[r]++; }
  FOREACH_T(HIT)
#undef HIT
  unsigned q01 = (unsigned)h[0] | ((unsigned)h[1] << 16);
  unsigned q23 = (unsigned)h[2] | ((unsigned)h[3] << 16);
#pragma unroll
  for (int m = 1; m <= 8; m <<= 1) {
    q01 += __shfl_xor(q01, m, 64);
    q23 += __shfl_xor(q23, m, 64);
  }
  if (cl == 0) {
    hitL[chh][rowbase + 0] = (int)(q01 & 0xffffu);
    hitL[chh][rowbase + 1] = (int)(q01 >> 16);
    hitL[chh][rowbase + 2] = (int)(q23 & 0xffffu);
    hitL[chh][rowbase + 3] = (int)(q23 >> 16);
  }
  __syncthreads();
  float scoreloc = 0.f;
  if (chh == 0 && cl == 0) {
#pragma unroll
    for (int r = 0; r < 4; ++r) {
      int hits = hitL[0][rowbase + r] + hitL[1][rowbase + r];
      if (hits > kr[r]) hits = kr[r];   // degenerate (tie/exhaustion) clamp
      scoreloc += (float)hits / (float)kr[r];
    }
  }

  // Block reduction -> one global atomic per block per output
#pragma unroll
  for (int m = 1; m < 64; m <<= 1) {
    lossloc  += __shfl_xor(lossloc, m, 64);
    scoreloc += __shfl_xor(scoreloc, m, 64);
  }
  if (lane == 0) { redL[wave] = lossloc; redS[wave] = scoreloc; }
  __syncthreads();
  if (tid == 0) {
    atomicAdd(&accum[0], redL[0] + redL[1] + redL[2] + redL[3]);
    atomicAdd(&accum[1], redS[0] + redS[1] + redS[2] + redS[3]);
  }
}

__global__ void wcvt_kernel(const float* __restrict__ W, short* __restrict__ Wbf) {
  int idx = (blockIdx.x * 256 + threadIdx.x) * 4;   // elem in [544*512]
  int row = idx >> 9;
  bf16x4 v = {0, 0, 0, 0};
  if (row < CC) {
    f32x4 f = *(const f32x4*)(W + idx);             // idx = row*512+col, row<527
    v[0]=f2bf(f.x); v[1]=f2bf(f.y); v[2]=f2bf(f.z); v[3]=f2bf(f.w);
  }
  *(bf16x4*)(Wbf + idx) = v;
}

__global__ void init_ws_kernel(float* ws) {
  ws[0] = 0.f;
  ws[1] = 0.f;
}

__global__ void finalize_kernel(const float* __restrict__ ws, float* __restrict__ out) {
  out[0] = (float)((double)ws[0] / ((double)BB * (double)CC));
  out[1] = (float)((double)ws[1] / (double)BB);
}

extern "C" void kernel_launch(void* const* d_in, const int* in_sizes, int n_in,
                              void* d_out, int out_size, void* d_ws, size_t ws_size,
                              hipStream_t stream) {
  const float* x  = (const float*)d_in[0];
  const float* y  = (const float*)d_in[1];
  const float* W  = (const float*)d_in[2];
  const float* b  = (const float*)d_in[3];
  const float* pw = (const float*)d_in[4];
  float* out = (float*)d_out;
  float* ws  = (float*)d_ws;
  short* Wbf = (short*)((char*)d_ws + 64);

  const size_t need = 64 + (size_t)NCOL * DD * 2;
  const bool pre = (ws_size >= need);

  init_ws_kernel<<<dim3(1), dim3(1), 0, stream>>>(ws);
  if (pre) {
    wcvt_kernel<<<dim3(NCOL * DD / 1024), dim3(256), 0, stream>>>(W, Wbf);
    fused_mfma_bce_topk<true><<<dim3(BB / BM), dim3(256), 0, stream>>>(
        x, y, W, Wbf, b, pw, ws);
  } else {
    fused_mfma_bce_topk<false><<<dim3(BB / BM), dim3(256), 0, stream>>>(
        x, y, W, Wbf, b, pw, ws);
  }
  finalize_kernel<<<dim3(1), dim3(1), 0, stream>>>(ws, out);
}